// Round 8
// baseline (223.339 us; speedup 1.0000x reference)
//
#include <hip/hip_runtime.h>

#define NLOCAL 55000
#define NOWNED 50000
#define NEDGES 800000
#define INC 128
#define HIDC 128
#define OUTC 64
#define CAP 64            // padded-CSR bucket capacity (max degree; P(exceed) ~ 1e-15)
#define NSTRIPS (NOWNED / 16)   // 3125 exact
#define ZLD 136           // zt LDS row stride in shorts (+8 pad: phase-B ds_read 2-way/free)
#define NFILLB (NEDGES / 256)   // 3125 fill blocks
#define NPREPB ((NLOCAL * 32 + 255) / 256)   // 6875 prep blocks

typedef unsigned short ushort_t;
typedef unsigned int uint_t;
typedef short short8_t __attribute__((ext_vector_type(8)));
typedef float float4_t __attribute__((ext_vector_type(4)));

static __device__ __forceinline__ ushort_t f2bf(float f) {   // RNE fp32->bf16
    uint_t u = __float_as_uint(f);
    return (ushort_t)((u + 0x7FFFu + ((u >> 16) & 1u)) >> 16);
}
static __device__ __forceinline__ float bflo(uint_t v) { return __uint_as_float(v << 16); }
static __device__ __forceinline__ float bfhi(uint_t v) { return __uint_as_float(v & 0xFFFF0000u); }

// ===== fused fill + prep =====
// blocks [0, NFILLB): padded-CSR build — atomic bump + NON-TEMPORAL scattered store
//   (nt keeps the 2B scatters from churning partial dirty lines in 8 non-coherent L2s)
// blocks [NFILLB, ...): xd = bf16(deg*x); w1,w2 transpose to bf16 [n][k]
// (cnt zeroed by memset before this kernel; fill and prep touch disjoint data)
__global__ __launch_bounds__(256) void fillprep_k(const int* __restrict__ er,
                                                  const int* __restrict__ ec,
                                                  const float* __restrict__ x,
                                                  const float* __restrict__ deg,
                                                  const float* __restrict__ w1,
                                                  const float* __restrict__ w2,
                                                  int* __restrict__ cnt,
                                                  ushort_t* __restrict__ cols_pad,
                                                  ushort_t* __restrict__ xd,
                                                  ushort_t* __restrict__ w1t,
                                                  ushort_t* __restrict__ w2t) {
    if (blockIdx.x < NFILLB) {
        const int e = blockIdx.x * 256 + threadIdx.x;
        const int row = er[e];
        if (row >= NOWNED) return;              // only owned destination rows matter
        const int p = atomicAdd(&cnt[row], 1);
        if (p < CAP)
            __builtin_nontemporal_store((ushort_t)ec[e], &cols_pad[row * CAP + p]);
        return;
    }
    const int gid = (blockIdx.x - NFILLB) * 256 + threadIdx.x;
    if (gid < NLOCAL * 32) {                 // one float4 -> 4 bf16
        const int row = gid >> 5;
        const int c0 = (gid & 31) << 2;
        const float d = deg[row];
        const float4 v = *(const float4*)(x + (size_t)row * INC + c0);
        uint_t lo = (uint_t)f2bf(v.x * d) | ((uint_t)f2bf(v.y * d) << 16);
        uint_t hi = (uint_t)f2bf(v.z * d) | ((uint_t)f2bf(v.w * d) << 16);
        *(uint2*)(xd + (size_t)row * INC + c0) = make_uint2(lo, hi);
    }
    if (gid < HIDC * INC) {                  // w1 [K=128][N=128] -> w1t [N][K]
        const int k = gid >> 7, n = gid & 127;
        w1t[n * 128 + k] = f2bf(w1[gid]);
    } else if (gid < HIDC * INC + HIDC * OUTC) {   // w2 [K=128][N=64] -> w2t [N][K]
        const int j = gid - HIDC * INC;
        const int k = j >> 6, n = j & 63;
        w2t[n * 128 + k] = f2bf(w2[j]);
    }
}

// ========== layer-1 gather: agg1b[r] = bf16(sum_e xd[col])  (128 ch) ==========
// one wave per row; 4 edges/iter (16-lane quarters), uint4 = 8 ch/lane;
// wave-uniform scalar col loads (4 ushort cols per 8B), prefetched; fp32 acc, bf16 out
__global__ __launch_bounds__(256) void gather1_k(const ushort_t* __restrict__ xd,
                                                 const int* __restrict__ cnt,
                                                 const ushort_t* __restrict__ cols_pad,
                                                 ushort_t* __restrict__ agg1b) {
    const int w = __builtin_amdgcn_readfirstlane((blockIdx.x * 256 + threadIdx.x) >> 6);
    if (w >= NOWNED) return;
    const int lane = threadIdx.x & 63;
    const int q4 = lane >> 4;                   // quarter: edge 4j+q4
    const int ch = (lane & 15) << 3;            // 8 channels per lane (16 B)
    int n = cnt[w];
    n = (n > CAP) ? CAP : n;
    const uint2* cp = (const uint2*)(cols_pad + w * CAP);   // 4 cols per 8B scalar load
    const int nIter = (n + 3) >> 2;
    float a0 = 0.f, a1 = 0.f, a2 = 0.f, a3 = 0.f, a4 = 0.f, a5 = 0.f, a6 = 0.f, a7 = 0.f;
    uint2 cc = (nIter > 0) ? cp[0] : make_uint2(0, 0);
    for (int j = 0; j < nIter; ++j) {
        const uint2 cn = cp[(j + 1 < 16) ? j + 1 : 15];    // prefetch next (clamped)
        const int e = j * 4 + q4;
        int myc = (q4 == 0) ? (int)(cc.x & 0xFFFF) :
                  (q4 == 1) ? (int)(cc.x >> 16) :
                  (q4 == 2) ? (int)(cc.y & 0xFFFF) : (int)(cc.y >> 16);
        const float wgt = (e < n) ? 1.f : 0.f;
        myc = (e < n) ? myc : 0;
        const uint4 v = *(const uint4*)(xd + (size_t)myc * INC + ch);
        a0 = fmaf(wgt, bflo(v.x), a0);  a1 = fmaf(wgt, bfhi(v.x), a1);
        a2 = fmaf(wgt, bflo(v.y), a2);  a3 = fmaf(wgt, bfhi(v.y), a3);
        a4 = fmaf(wgt, bflo(v.z), a4);  a5 = fmaf(wgt, bfhi(v.z), a5);
        a6 = fmaf(wgt, bflo(v.w), a6);  a7 = fmaf(wgt, bfhi(v.w), a7);
        cc = cn;
    }
    // fold the 4 quarters together
    a0 += __shfl_xor(a0, 16); a1 += __shfl_xor(a1, 16); a2 += __shfl_xor(a2, 16); a3 += __shfl_xor(a3, 16);
    a4 += __shfl_xor(a4, 16); a5 += __shfl_xor(a5, 16); a6 += __shfl_xor(a6, 16); a7 += __shfl_xor(a7, 16);
    a0 += __shfl_xor(a0, 32); a1 += __shfl_xor(a1, 32); a2 += __shfl_xor(a2, 32); a3 += __shfl_xor(a3, 32);
    a4 += __shfl_xor(a4, 32); a5 += __shfl_xor(a5, 32); a6 += __shfl_xor(a6, 32); a7 += __shfl_xor(a7, 32);
    if (lane < 16) {
        uint4 o;
        o.x = (uint_t)f2bf(a0) | ((uint_t)f2bf(a1) << 16);
        o.y = (uint_t)f2bf(a2) | ((uint_t)f2bf(a3) << 16);
        o.z = (uint_t)f2bf(a4) | ((uint_t)f2bf(a5) << 16);
        o.w = (uint_t)f2bf(a6) | ((uint_t)f2bf(a7) << 16);
        *(uint4*)(agg1b + (size_t)w * INC + ch) = o;
    }
}

// ===== fused gemm1+gemm2 (MFMA): h2 = bf16( relu(d*(agg1b@w1)+b1)*d @ w2 )  per 16-row strip =====
// block = 4 waves = one strip; gemm1 C-tile round-trips LDS (C-layout -> A-layout), feeds gemm2
__global__ __launch_bounds__(256) void gemm12_k(const ushort_t* __restrict__ agg1b,
                                                const ushort_t* __restrict__ w1t,
                                                const ushort_t* __restrict__ w2t,
                                                const float* __restrict__ b1,
                                                const float* __restrict__ deg,
                                                ushort_t* __restrict__ h2) {
    __shared__ ushort_t zt[16 * ZLD];           // 16 rows x 128 ch (+8 pad), 4.25 KB
    const int wv = threadIdx.x >> 6, lane = threadIdx.x & 63;
    const int strip = blockIdx.x;
    const int row0 = strip * 16;
    const int m = lane & 15, q = lane >> 4;

    // ---- phase A: z-tile = relu(d*(agg1b@w1)+b1)*d ; each wave does 2 of 8 n-tiles ----
    float4_t acc[2];
    acc[0] = (float4_t){0.f, 0.f, 0.f, 0.f};
    acc[1] = (float4_t){0.f, 0.f, 0.f, 0.f};
    #pragma unroll
    for (int ks = 0; ks < 4; ++ks) {
        const int k0 = ks * 32 + q * 8;
        const short8_t a = *(const short8_t*)(agg1b + (size_t)(row0 + m) * HIDC + k0);
        #pragma unroll
        for (int t = 0; t < 2; ++t) {
            const int nt = wv * 2 + t;
            const short8_t b = *(const short8_t*)(w1t + (size_t)(nt * 16 + m) * HIDC + k0);
            acc[t] = __builtin_amdgcn_mfma_f32_16x16x32_bf16(a, b, acc[t], 0, 0, 0);
        }
    }
    #pragma unroll
    for (int reg = 0; reg < 4; ++reg) {
        const int r = q * 4 + reg;              // row within strip
        const float d = deg[row0 + r];
        #pragma unroll
        for (int t = 0; t < 2; ++t) {
            const int col = (wv * 2 + t) * 16 + m;
            float v = fmaf(d, acc[t][reg], b1[col]);
            zt[r * ZLD + col] = f2bf(fmaxf(v, 0.f) * d);   // relu + fold layer-2 left d-scale
        }
    }
    __syncthreads();

    // ---- phase B: h2-tile = z @ w2 ; each wave does 1 of 4 n-tiles ----
    float4_t acc2 = (float4_t){0.f, 0.f, 0.f, 0.f};
    #pragma unroll
    for (int ks = 0; ks < 4; ++ks) {
        const int k0 = ks * 32 + q * 8;
        const short8_t a = *(const short8_t*)(&zt[m * ZLD + k0]);
        const short8_t b = *(const short8_t*)(w2t + (size_t)(wv * 16 + m) * HIDC + k0);
        acc2 = __builtin_amdgcn_mfma_f32_16x16x32_bf16(a, b, acc2, 0, 0, 0);
    }
    #pragma unroll
    for (int reg = 0; reg < 4; ++reg) {
        const int row = row0 + q * 4 + reg;
        h2[(size_t)row * OUTC + wv * 16 + m] = f2bf(acc2[reg]);
    }
}

// ===== layer-2 gather + epilogue: out[r] = deg[r]*sum(h2[col<NOWNED]) + b2 =====
// 4 edges/iter (quarters), uint2 = 4 ch/lane; scalar ushort-col loads w/ prefetch
__global__ __launch_bounds__(256) void gather2_k(const ushort_t* __restrict__ h2,
                                                 const float* __restrict__ deg,
                                                 const float* __restrict__ b2,
                                                 const int* __restrict__ cnt,
                                                 const ushort_t* __restrict__ cols_pad,
                                                 float* __restrict__ out) {
    const int w = __builtin_amdgcn_readfirstlane((blockIdx.x * 256 + threadIdx.x) >> 6);
    if (w >= NOWNED) return;
    const int lane = threadIdx.x & 63;
    const int q4 = lane >> 4;
    const int ch = (lane & 15) << 2;            // 4 channels per lane (8 B)
    int n = cnt[w];
    n = (n > CAP) ? CAP : n;
    const uint2* cp = (const uint2*)(cols_pad + w * CAP);
    const int nIter = (n + 3) >> 2;
    float a0 = 0.f, a1 = 0.f, a2 = 0.f, a3 = 0.f;
    uint2 cc = (nIter > 0) ? cp[0] : make_uint2(0, 0);
    for (int j = 0; j < nIter; ++j) {
        const uint2 cn = cp[(j + 1 < 16) ? j + 1 : 15];
        const int e = j * 4 + q4;
        int myc = (q4 == 0) ? (int)(cc.x & 0xFFFF) :
                  (q4 == 1) ? (int)(cc.x >> 16) :
                  (q4 == 2) ? (int)(cc.y & 0xFFFF) : (int)(cc.y >> 16);
        const float wgt = (e < n && myc < NOWNED) ? 1.f : 0.f;  // halo rows of x2 are zero
        myc = (e < n && myc < NOWNED) ? myc : 0;
        const uint2 v = *(const uint2*)(h2 + (size_t)myc * OUTC + ch);
        a0 = fmaf(wgt, bflo(v.x), a0);  a1 = fmaf(wgt, bfhi(v.x), a1);
        a2 = fmaf(wgt, bflo(v.y), a2);  a3 = fmaf(wgt, bfhi(v.y), a3);
        cc = cn;
    }
    a0 += __shfl_xor(a0, 16); a1 += __shfl_xor(a1, 16); a2 += __shfl_xor(a2, 16); a3 += __shfl_xor(a3, 16);
    a0 += __shfl_xor(a0, 32); a1 += __shfl_xor(a1, 32); a2 += __shfl_xor(a2, 32); a3 += __shfl_xor(a3, 32);
    if (lane < 16) {
        const float d = deg[w];
        const float4 o = make_float4(fmaf(d, a0, b2[ch]),     fmaf(d, a1, b2[ch + 1]),
                                     fmaf(d, a2, b2[ch + 2]), fmaf(d, a3, b2[ch + 3]));
        *(float4*)(out + (size_t)w * OUTC + ch) = o;
    }
}

extern "C" void kernel_launch(void* const* d_in, const int* in_sizes, int n_in,
                              void* d_out, int out_size, void* d_ws, size_t ws_size,
                              hipStream_t stream) {
    const float* x   = (const float*)d_in[0];
    const float* deg = (const float*)d_in[1];
    const float* w1  = (const float*)d_in[2];
    const float* b1  = (const float*)d_in[3];
    const float* w2  = (const float*)d_in[4];
    const float* b2  = (const float*)d_in[5];
    const int* er    = (const int*)d_in[6];
    const int* ec    = (const int*)d_in[7];
    float* out = (float*)d_out;

    char* ws = (char*)d_ws;
    ushort_t* xd       = (ushort_t*)(ws);              // 14.08 MB [NLOCAL x 128] bf16
    ushort_t* cols_pad = (ushort_t*)(ws + 14090240);   // 6.4 MB   [NOWNED x CAP] ushort
    int* cnt           = (int*)(ws + 20490240);        // 200 KB   [NOWNED] compact
    ushort_t* agg1b    = (ushort_t*)(ws + 20690944);   // 12.8 MB  [NOWNED x 128] bf16
    ushort_t* h2       = (ushort_t*)(ws + 33490944);   // 6.4 MB   [NOWNED x 64] bf16
    ushort_t* w1t      = (ushort_t*)(ws + 39890944);   // 32 KB    [128 x 128] bf16
    ushort_t* w2t      = (ushort_t*)(ws + 39923712);   // 16 KB    [64 x 128] bf16

    // memset(cnt) -> fused fill+prep -> gather1 -> fused gemms -> gather2
    hipMemsetAsync(cnt, 0, NOWNED * sizeof(int), stream);
    fillprep_k<<<NFILLB + NPREPB, 256, 0, stream>>>(er, ec, x, deg, w1, w2,
                                                    cnt, cols_pad, xd, w1t, w2t);
    gather1_k<<<(NOWNED * 64 + 255) / 256, 256, 0, stream>>>(xd, cnt, cols_pad, agg1b);
    gemm12_k<<<NSTRIPS, 256, 0, stream>>>(agg1b, w1t, w2t, b1, deg, h2);
    gather2_k<<<(NOWNED * 64 + 255) / 256, 256, 0, stream>>>(h2, deg, b2, cnt, cols_pad, out);
}

// Round 9
// 194.032 us; speedup vs baseline: 1.1510x; 1.1510x over previous
//
#include <hip/hip_runtime.h>

#define NLOCAL 55000
#define NOWNED 50000
#define NEDGES 800000
#define INC 128
#define HIDC 128
#define OUTC 64
#define CAP 64            // per-row CSR capacity (deg ~ Binom mean 14.5; P(>64) ~ 1e-15)
#define NSTRIPS (NOWNED / 16)   // 3125
#define ZLD 136           // zt LDS row stride in shorts (+8 pad)
#define NB 256            // bin_k blocks (private regions)
#define EPB (NEDGES / NB) // 3125 edges per bin block
#define NBUCK 391         // row buckets of 128 rows (50048 padded rows)
#define BROWS 128
#define BCAP 64           // per (block,bucket) capacity (mean 8; P(>64) ~ 1e-20)
#define NROWS_PAD (NBUCK * BROWS)   // 50048

typedef unsigned short ushort_t;
typedef unsigned int uint_t;
typedef short short8_t __attribute__((ext_vector_type(8)));
typedef float float4_t __attribute__((ext_vector_type(4)));

static __device__ __forceinline__ ushort_t f2bf(float f) {   // RNE fp32->bf16
    uint_t u = __float_as_uint(f);
    return (ushort_t)((u + 0x7FFFu + ((u >> 16) & 1u)) >> 16);
}
static __device__ __forceinline__ float bflo(uint_t v) { return __uint_as_float(v << 16); }
static __device__ __forceinline__ float bfhi(uint_t v) { return __uint_as_float(v & 0xFFFF0000u); }

// ======= prep: xd = bf16(deg*x); transpose w1,w2 to bf16 [n][k] =======
__global__ __launch_bounds__(256) void prep_k(const float* __restrict__ x,
                                              const float* __restrict__ deg,
                                              const float* __restrict__ w1,
                                              const float* __restrict__ w2,
                                              ushort_t* __restrict__ xd,
                                              ushort_t* __restrict__ w1t,
                                              ushort_t* __restrict__ w2t) {
    const int gid = blockIdx.x * 256 + threadIdx.x;
    if (gid < NLOCAL * 32) {                 // one float4 -> 4 bf16
        const int row = gid >> 5;
        const int c0 = (gid & 31) << 2;
        const float d = deg[row];
        const float4 v = *(const float4*)(x + (size_t)row * INC + c0);
        uint_t lo = (uint_t)f2bf(v.x * d) | ((uint_t)f2bf(v.y * d) << 16);
        uint_t hi = (uint_t)f2bf(v.z * d) | ((uint_t)f2bf(v.w * d) << 16);
        *(uint2*)(xd + (size_t)row * INC + c0) = make_uint2(lo, hi);
    }
    if (gid < HIDC * INC) {                  // w1 [K][N=128] -> w1t [N][K]
        const int k = gid >> 7, n = gid & 127;
        w1t[n * 128 + k] = f2bf(w1[gid]);
    } else if (gid < HIDC * INC + HIDC * OUTC) {   // w2 [K][N=64] -> w2t [N][K]
        const int j = gid - HIDC * INC;
        const int k = j >> 6, n = j & 63;
        w2t[n * 128 + k] = f2bf(w2[j]);
    }
}

// ===== pass 1: bin edges into per-BLOCK-private bucket regions (no global atomics) =====
// bbuf[k][b][p] = (row&127)<<16 | col ; each region written by exactly one CU -> no
// cross-XCD partial-line churn (the measured fill_k failure mode)
__global__ __launch_bounds__(256) void bin_k(const int* __restrict__ er,
                                             const int* __restrict__ ec,
                                             int* __restrict__ bcnt2,
                                             uint_t* __restrict__ bbuf) {
    __shared__ int lcnt[NBUCK];
    const int k = blockIdx.x;
    for (int b = threadIdx.x; b < NBUCK; b += 256) lcnt[b] = 0;
    __syncthreads();
    const int e0 = k * EPB;
    for (int i = threadIdx.x; i < EPB; i += 256) {
        const int e = e0 + i;
        const int row = er[e];
        if (row >= NOWNED) continue;            // only owned destination rows matter
        const int col = ec[e];
        const int b = row >> 7;
        const int p = atomicAdd(&lcnt[b], 1);   // LDS atomic
        if (p < BCAP)
            bbuf[((size_t)k * NBUCK + b) * BCAP + p] = ((uint_t)(row & 127) << 16) | (uint_t)col;
    }
    __syncthreads();
    for (int b = threadIdx.x; b < NBUCK; b += 256) {
        const int c = lcnt[b];
        bcnt2[k * NBUCK + b] = (c > BCAP) ? BCAP : c;   // coalesced per-block write
    }
}

// ===== pass 2: bucket -> padded CSR; all global writes are coalesced streaming =====
// block b: thread t drains region t's bucket-b slice into LDS per-row lists
__global__ __launch_bounds__(256) void csr_k(const int* __restrict__ bcnt2,
                                             const uint_t* __restrict__ bbuf,
                                             int* __restrict__ cnt,
                                             ushort_t* __restrict__ cols_pad) {
    __shared__ int lcnt[BROWS];
    __shared__ ushort_t lcols[BROWS * CAP];     // 16 KB
    const int b = blockIdx.x;
    const int t = threadIdx.x;                  // == region index (NB == 256)
    if (t < BROWS) lcnt[t] = 0;
    __syncthreads();
    const int n = bcnt2[t * NBUCK + b];
    const uint_t* src = bbuf + ((size_t)t * NBUCK + b) * BCAP;
    for (int i = 0; i < n; ++i) {
        const uint_t v = src[i];
        const int rl = (int)(v >> 16);
        const int p = atomicAdd(&lcnt[rl], 1);
        if (p < CAP) lcols[rl * CAP + p] = (ushort_t)(v & 0xFFFFu);
    }
    __syncthreads();
    const int row0 = b * BROWS;
    if (t < BROWS) {
        const int c = lcnt[t];
        cnt[row0 + t] = (c > CAP) ? CAP : c;    // coalesced
    }
    const uint4* ls = (const uint4*)lcols;      // 1024 x 16B
    uint4* gd = (uint4*)(cols_pad + (size_t)row0 * CAP);
    #pragma unroll
    for (int i = 0; i < BROWS * CAP / 8 / 256; ++i)   // 4 per thread
        gd[t + i * 256] = ls[t + i * 256];      // streaming, full lines
}

// ========== layer-1 gather: agg1b[r] = bf16(sum_e xd[col])  (128 ch) ==========
__global__ __launch_bounds__(256) void gather1_k(const ushort_t* __restrict__ xd,
                                                 const int* __restrict__ cnt,
                                                 const ushort_t* __restrict__ cols_pad,
                                                 ushort_t* __restrict__ agg1b) {
    const int w = __builtin_amdgcn_readfirstlane((blockIdx.x * 256 + threadIdx.x) >> 6);
    if (w >= NOWNED) return;
    const int lane = threadIdx.x & 63;
    const int q4 = lane >> 4;                   // quarter: edge 4j+q4
    const int ch = (lane & 15) << 3;            // 8 channels per lane (16 B)
    int n = cnt[w];
    n = (n > CAP) ? CAP : n;
    const uint2* cp = (const uint2*)(cols_pad + w * CAP);   // 4 cols per 8B scalar load
    const int nIter = (n + 3) >> 2;
    float a0 = 0.f, a1 = 0.f, a2 = 0.f, a3 = 0.f, a4 = 0.f, a5 = 0.f, a6 = 0.f, a7 = 0.f;
    uint2 cc = (nIter > 0) ? cp[0] : make_uint2(0, 0);
    for (int j = 0; j < nIter; ++j) {
        const uint2 cn = cp[(j + 1 < 16) ? j + 1 : 15];    // prefetch next (clamped)
        const int e = j * 4 + q4;
        int myc = (q4 == 0) ? (int)(cc.x & 0xFFFF) :
                  (q4 == 1) ? (int)(cc.x >> 16) :
                  (q4 == 2) ? (int)(cc.y & 0xFFFF) : (int)(cc.y >> 16);
        const float wgt = (e < n) ? 1.f : 0.f;
        myc = (e < n) ? myc : 0;
        const uint4 v = *(const uint4*)(xd + (size_t)myc * INC + ch);
        a0 = fmaf(wgt, bflo(v.x), a0);  a1 = fmaf(wgt, bfhi(v.x), a1);
        a2 = fmaf(wgt, bflo(v.y), a2);  a3 = fmaf(wgt, bfhi(v.y), a3);
        a4 = fmaf(wgt, bflo(v.z), a4);  a5 = fmaf(wgt, bfhi(v.z), a5);
        a6 = fmaf(wgt, bflo(v.w), a6);  a7 = fmaf(wgt, bfhi(v.w), a7);
        cc = cn;
    }
    a0 += __shfl_xor(a0, 16); a1 += __shfl_xor(a1, 16); a2 += __shfl_xor(a2, 16); a3 += __shfl_xor(a3, 16);
    a4 += __shfl_xor(a4, 16); a5 += __shfl_xor(a5, 16); a6 += __shfl_xor(a6, 16); a7 += __shfl_xor(a7, 16);
    a0 += __shfl_xor(a0, 32); a1 += __shfl_xor(a1, 32); a2 += __shfl_xor(a2, 32); a3 += __shfl_xor(a3, 32);
    a4 += __shfl_xor(a4, 32); a5 += __shfl_xor(a5, 32); a6 += __shfl_xor(a6, 32); a7 += __shfl_xor(a7, 32);
    if (lane < 16) {
        uint4 o;
        o.x = (uint_t)f2bf(a0) | ((uint_t)f2bf(a1) << 16);
        o.y = (uint_t)f2bf(a2) | ((uint_t)f2bf(a3) << 16);
        o.z = (uint_t)f2bf(a4) | ((uint_t)f2bf(a5) << 16);
        o.w = (uint_t)f2bf(a6) | ((uint_t)f2bf(a7) << 16);
        *(uint4*)(agg1b + (size_t)w * INC + ch) = o;
    }
}

// ===== fused gemm1+gemm2 (MFMA): h2 = bf16( relu(d*(agg1b@w1)+b1)*d @ w2 ) per 16-row strip =====
__global__ __launch_bounds__(256) void gemm12_k(const ushort_t* __restrict__ agg1b,
                                                const ushort_t* __restrict__ w1t,
                                                const ushort_t* __restrict__ w2t,
                                                const float* __restrict__ b1,
                                                const float* __restrict__ deg,
                                                ushort_t* __restrict__ h2) {
    __shared__ ushort_t zt[16 * ZLD];
    const int wv = threadIdx.x >> 6, lane = threadIdx.x & 63;
    const int row0 = blockIdx.x * 16;
    const int m = lane & 15, q = lane >> 4;

    float4_t acc[2];
    acc[0] = (float4_t){0.f, 0.f, 0.f, 0.f};
    acc[1] = (float4_t){0.f, 0.f, 0.f, 0.f};
    #pragma unroll
    for (int ks = 0; ks < 4; ++ks) {
        const int k0 = ks * 32 + q * 8;
        const short8_t a = *(const short8_t*)(agg1b + (size_t)(row0 + m) * HIDC + k0);
        #pragma unroll
        for (int t = 0; t < 2; ++t) {
            const int nt = wv * 2 + t;
            const short8_t b = *(const short8_t*)(w1t + (size_t)(nt * 16 + m) * HIDC + k0);
            acc[t] = __builtin_amdgcn_mfma_f32_16x16x32_bf16(a, b, acc[t], 0, 0, 0);
        }
    }
    #pragma unroll
    for (int reg = 0; reg < 4; ++reg) {
        const int r = q * 4 + reg;
        const float d = deg[row0 + r];
        #pragma unroll
        for (int t = 0; t < 2; ++t) {
            const int col = (wv * 2 + t) * 16 + m;
            float v = fmaf(d, acc[t][reg], b1[col]);
            zt[r * ZLD + col] = f2bf(fmaxf(v, 0.f) * d);   // relu + fold layer-2 left d-scale
        }
    }
    __syncthreads();

    float4_t acc2 = (float4_t){0.f, 0.f, 0.f, 0.f};
    #pragma unroll
    for (int ks = 0; ks < 4; ++ks) {
        const int k0 = ks * 32 + q * 8;
        const short8_t a = *(const short8_t*)(&zt[m * ZLD + k0]);
        const short8_t b = *(const short8_t*)(w2t + (size_t)(wv * 16 + m) * HIDC + k0);
        acc2 = __builtin_amdgcn_mfma_f32_16x16x32_bf16(a, b, acc2, 0, 0, 0);
    }
    #pragma unroll
    for (int reg = 0; reg < 4; ++reg) {
        const int row = row0 + q * 4 + reg;
        h2[(size_t)row * OUTC + wv * 16 + m] = f2bf(acc2[reg]);
    }
}

// ===== layer-2 gather + epilogue: out[r] = deg[r]*sum(h2[col<NOWNED]) + b2 =====
__global__ __launch_bounds__(256) void gather2_k(const ushort_t* __restrict__ h2,
                                                 const float* __restrict__ deg,
                                                 const float* __restrict__ b2,
                                                 const int* __restrict__ cnt,
                                                 const ushort_t* __restrict__ cols_pad,
                                                 float* __restrict__ out) {
    const int w = __builtin_amdgcn_readfirstlane((blockIdx.x * 256 + threadIdx.x) >> 6);
    if (w >= NOWNED) return;
    const int lane = threadIdx.x & 63;
    const int q4 = lane >> 4;
    const int ch = (lane & 15) << 2;            // 4 channels per lane (8 B)
    int n = cnt[w];
    n = (n > CAP) ? CAP : n;
    const uint2* cp = (const uint2*)(cols_pad + w * CAP);
    const int nIter = (n + 3) >> 2;
    float a0 = 0.f, a1 = 0.f, a2 = 0.f, a3 = 0.f;
    uint2 cc = (nIter > 0) ? cp[0] : make_uint2(0, 0);
    for (int j = 0; j < nIter; ++j) {
        const uint2 cn = cp[(j + 1 < 16) ? j + 1 : 15];
        const int e = j * 4 + q4;
        int myc = (q4 == 0) ? (int)(cc.x & 0xFFFF) :
                  (q4 == 1) ? (int)(cc.x >> 16) :
                  (q4 == 2) ? (int)(cc.y & 0xFFFF) : (int)(cc.y >> 16);
        const float wgt = (e < n && myc < NOWNED) ? 1.f : 0.f;  // halo rows of x2 are zero
        myc = (e < n && myc < NOWNED) ? myc : 0;
        const uint2 v = *(const uint2*)(h2 + (size_t)myc * OUTC + ch);
        a0 = fmaf(wgt, bflo(v.x), a0);  a1 = fmaf(wgt, bfhi(v.x), a1);
        a2 = fmaf(wgt, bflo(v.y), a2);  a3 = fmaf(wgt, bfhi(v.y), a3);
        cc = cn;
    }
    a0 += __shfl_xor(a0, 16); a1 += __shfl_xor(a1, 16); a2 += __shfl_xor(a2, 16); a3 += __shfl_xor(a3, 16);
    a0 += __shfl_xor(a0, 32); a1 += __shfl_xor(a1, 32); a2 += __shfl_xor(a2, 32); a3 += __shfl_xor(a3, 32);
    if (lane < 16) {
        const float d = deg[w];
        const float4 o = make_float4(fmaf(d, a0, b2[ch]),     fmaf(d, a1, b2[ch + 1]),
                                     fmaf(d, a2, b2[ch + 2]), fmaf(d, a3, b2[ch + 3]));
        *(float4*)(out + (size_t)w * OUTC + ch) = o;
    }
}

extern "C" void kernel_launch(void* const* d_in, const int* in_sizes, int n_in,
                              void* d_out, int out_size, void* d_ws, size_t ws_size,
                              hipStream_t stream) {
    const float* x   = (const float*)d_in[0];
    const float* deg = (const float*)d_in[1];
    const float* w1  = (const float*)d_in[2];
    const float* b1  = (const float*)d_in[3];
    const float* w2  = (const float*)d_in[4];
    const float* b2  = (const float*)d_in[5];
    const int* er    = (const int*)d_in[6];
    const int* ec    = (const int*)d_in[7];
    float* out = (float*)d_out;

    char* ws = (char*)d_ws;
    ushort_t* xd       = (ushort_t*)(ws);              // 14.08 MB [NLOCAL x 128] bf16
    ushort_t* cols_pad = (ushort_t*)(ws + 14080000);   // 6.41 MB  [NROWS_PAD x CAP] ushort
    int* cnt           = (int*)(ws + 20486144);        // 200 KB   [NROWS_PAD]
    ushort_t* agg1b    = (ushort_t*)(ws + 20686336);   // 12.8 MB  [NOWNED x 128] bf16
    ushort_t* h2       = (ushort_t*)(ws + 33486336);   // 6.4 MB   [NOWNED x 64] bf16
    ushort_t* w1t      = (ushort_t*)(ws + 39886336);   // 32 KB    [128 x 128] bf16
    ushort_t* w2t      = (ushort_t*)(ws + 39919104);   // 16 KB    [64 x 128] bf16
    uint_t* bbuf       = (uint_t*)(ws + 39935488);     // 25.6 MB  [NB x NBUCK x BCAP]
    int* bcnt2         = (int*)(ws + 65560064);        // 400 KB   [NB x NBUCK]

    prep_k<<<(NLOCAL * 32 + 255) / 256, 256, 0, stream>>>(x, deg, w1, w2, xd, w1t, w2t);
    bin_k<<<NB, 256, 0, stream>>>(er, ec, bcnt2, bbuf);
    csr_k<<<NBUCK, 256, 0, stream>>>(bcnt2, bbuf, cnt, cols_pad);
    gather1_k<<<(NOWNED * 64 + 255) / 256, 256, 0, stream>>>(xd, cnt, cols_pad, agg1b);
    gemm12_k<<<NSTRIPS, 256, 0, stream>>>(agg1b, w1t, w2t, b1, deg, h2);
    gather2_k<<<(NOWNED * 64 + 255) / 256, 256, 0, stream>>>(h2, deg, b2, cnt, cols_pad, out);
}

// Round 10
// 180.877 us; speedup vs baseline: 1.2348x; 1.0727x over previous
//
#include <hip/hip_runtime.h>

#define NLOCAL 55000
#define NOWNED 50000
#define NEDGES 800000
#define INC 128
#define HIDC 128
#define OUTC 64
#define CAP 64            // per-row CSR capacity (deg ~ Binom mean 14.5; P(>64) ~ 1e-15)
#define NSTRIPS (NOWNED / 16)   // 3125
#define ZLD 136           // LDS tile row stride in shorts (+8 pad)
#define NB 256            // bin_k blocks (private regions)
#define EPB (NEDGES / NB) // 3125 edges per bin block
#define NBUCK 391         // row buckets of 128 rows (50048 padded rows)
#define BROWS 128
#define BCAP 64           // per (block,bucket) capacity (mean 8; P(>64) ~ 1e-20)
#define NROWS_PAD (NBUCK * BROWS)   // 50048

typedef unsigned short ushort_t;
typedef unsigned int uint_t;
typedef short short8_t __attribute__((ext_vector_type(8)));
typedef float float4_t __attribute__((ext_vector_type(4)));

static __device__ __forceinline__ ushort_t f2bf(float f) {   // RNE fp32->bf16
    uint_t u = __float_as_uint(f);
    return (ushort_t)((u + 0x7FFFu + ((u >> 16) & 1u)) >> 16);
}
static __device__ __forceinline__ float bflo(uint_t v) { return __uint_as_float(v << 16); }
static __device__ __forceinline__ float bfhi(uint_t v) { return __uint_as_float(v & 0xFFFF0000u); }

// ======= prep: xd = bf16(deg*x); transpose w1,w2 to bf16 [n][k] =======
__global__ __launch_bounds__(256) void prep_k(const float* __restrict__ x,
                                              const float* __restrict__ deg,
                                              const float* __restrict__ w1,
                                              const float* __restrict__ w2,
                                              ushort_t* __restrict__ xd,
                                              ushort_t* __restrict__ w1t,
                                              ushort_t* __restrict__ w2t) {
    const int gid = blockIdx.x * 256 + threadIdx.x;
    if (gid < NLOCAL * 32) {                 // one float4 -> 4 bf16
        const int row = gid >> 5;
        const int c0 = (gid & 31) << 2;
        const float d = deg[row];
        const float4 v = *(const float4*)(x + (size_t)row * INC + c0);
        uint_t lo = (uint_t)f2bf(v.x * d) | ((uint_t)f2bf(v.y * d) << 16);
        uint_t hi = (uint_t)f2bf(v.z * d) | ((uint_t)f2bf(v.w * d) << 16);
        *(uint2*)(xd + (size_t)row * INC + c0) = make_uint2(lo, hi);
    }
    if (gid < HIDC * INC) {                  // w1 [K][N=128] -> w1t [N][K]
        const int k = gid >> 7, n = gid & 127;
        w1t[n * 128 + k] = f2bf(w1[gid]);
    } else if (gid < HIDC * INC + HIDC * OUTC) {   // w2 [K][N=64] -> w2t [N][K]
        const int j = gid - HIDC * INC;
        const int k = j >> 6, n = j & 63;
        w2t[n * 128 + k] = f2bf(w2[j]);
    }
}

// ===== pass 1: bin edges into per-BLOCK-private bucket regions (no global atomics) =====
__global__ __launch_bounds__(256) void bin_k(const int* __restrict__ er,
                                             const int* __restrict__ ec,
                                             int* __restrict__ bcnt2,
                                             uint_t* __restrict__ bbuf) {
    __shared__ int lcnt[NBUCK];
    const int k = blockIdx.x;
    for (int b = threadIdx.x; b < NBUCK; b += 256) lcnt[b] = 0;
    __syncthreads();
    const int e0 = k * EPB;
    for (int i = threadIdx.x; i < EPB; i += 256) {
        const int e = e0 + i;
        const int row = er[e];
        if (row >= NOWNED) continue;            // only owned destination rows matter
        const int col = ec[e];
        const int b = row >> 7;
        const int p = atomicAdd(&lcnt[b], 1);   // LDS atomic
        if (p < BCAP)
            bbuf[((size_t)k * NBUCK + b) * BCAP + p] = ((uint_t)(row & 127) << 16) | (uint_t)col;
    }
    __syncthreads();
    for (int b = threadIdx.x; b < NBUCK; b += 256) {
        const int c = lcnt[b];
        bcnt2[k * NBUCK + b] = (c > BCAP) ? BCAP : c;
    }
}

// ===== pass 2: bucket -> padded CSR; all global writes are coalesced streaming =====
__global__ __launch_bounds__(256) void csr_k(const int* __restrict__ bcnt2,
                                             const uint_t* __restrict__ bbuf,
                                             int* __restrict__ cnt,
                                             ushort_t* __restrict__ cols_pad) {
    __shared__ int lcnt[BROWS];
    __shared__ ushort_t lcols[BROWS * CAP];     // 16 KB
    const int b = blockIdx.x;
    const int t = threadIdx.x;                  // == region index (NB == 256)
    if (t < BROWS) lcnt[t] = 0;
    __syncthreads();
    const int n = bcnt2[t * NBUCK + b];
    const uint_t* src = bbuf + ((size_t)t * NBUCK + b) * BCAP;
    for (int i = 0; i < n; ++i) {
        const uint_t v = src[i];
        const int rl = (int)(v >> 16);
        const int p = atomicAdd(&lcnt[rl], 1);
        if (p < CAP) lcols[rl * CAP + p] = (ushort_t)(v & 0xFFFFu);
    }
    __syncthreads();
    const int row0 = b * BROWS;
    if (t < BROWS) {
        const int c = lcnt[t];
        cnt[row0 + t] = (c > CAP) ? CAP : c;
    }
    const uint4* ls = (const uint4*)lcols;      // 1024 x 16B
    uint4* gd = (uint4*)(cols_pad + (size_t)row0 * CAP);
    #pragma unroll
    for (int i = 0; i < BROWS * CAP / 8 / 256; ++i)   // 4 per thread
        gd[t + i * 256] = ls[t + i * 256];      // streaming, full lines
}

// ===== fused gather1 + gemm1 + gemm2 per 16-row strip =====
// phase 0: 4 waves x 4 rows — gather row-sums of xd[col] straight into LDS A-tile (bf16)
// phase A: z-tile = relu(d*(A@w1)+b1)*d -> LDS ;  phase B: h2 = bf16(z @ w2)
__global__ __launch_bounds__(256) void gg_k(const ushort_t* __restrict__ xd,
                                            const int* __restrict__ cnt,
                                            const ushort_t* __restrict__ cols_pad,
                                            const ushort_t* __restrict__ w1t,
                                            const ushort_t* __restrict__ w2t,
                                            const float* __restrict__ b1,
                                            const float* __restrict__ deg,
                                            ushort_t* __restrict__ h2) {
    __shared__ ushort_t at[16 * ZLD];           // gathered A-tile
    __shared__ ushort_t zt[16 * ZLD];           // layer-1 output tile
    const int lane = threadIdx.x & 63;
    const int wv = __builtin_amdgcn_readfirstlane(threadIdx.x >> 6);
    const int row0 = blockIdx.x * 16;
    const int q4 = lane >> 4;                   // quarter: edge 4j+q4
    const int ch = (lane & 15) << 3;            // 8 channels per lane (16 B)

    // ---- phase 0: gather 4 rows per wave ----
    for (int i = 0; i < 4; ++i) {
        const int rl = wv * 4 + i;
        const int w = row0 + rl;                // wave-uniform
        int n = cnt[w];
        n = (n > CAP) ? CAP : n;
        const uint2* cp = (const uint2*)(cols_pad + (size_t)w * CAP);  // 4 cols / 8B s_load
        const int nIter = (n + 3) >> 2;
        float a0 = 0.f, a1 = 0.f, a2 = 0.f, a3 = 0.f, a4 = 0.f, a5 = 0.f, a6 = 0.f, a7 = 0.f;
        uint2 cc = (nIter > 0) ? cp[0] : make_uint2(0, 0);
        for (int j = 0; j < nIter; ++j) {
            const uint2 cn = cp[(j + 1 < 16) ? j + 1 : 15];   // prefetch next (clamped)
            const int e = j * 4 + q4;
            int myc = (q4 == 0) ? (int)(cc.x & 0xFFFF) :
                      (q4 == 1) ? (int)(cc.x >> 16) :
                      (q4 == 2) ? (int)(cc.y & 0xFFFF) : (int)(cc.y >> 16);
            const float wgt = (e < n) ? 1.f : 0.f;
            myc = (e < n) ? myc : 0;
            const uint4 v = *(const uint4*)(xd + (size_t)myc * INC + ch);
            a0 = fmaf(wgt, bflo(v.x), a0);  a1 = fmaf(wgt, bfhi(v.x), a1);
            a2 = fmaf(wgt, bflo(v.y), a2);  a3 = fmaf(wgt, bfhi(v.y), a3);
            a4 = fmaf(wgt, bflo(v.z), a4);  a5 = fmaf(wgt, bfhi(v.z), a5);
            a6 = fmaf(wgt, bflo(v.w), a6);  a7 = fmaf(wgt, bfhi(v.w), a7);
            cc = cn;
        }
        a0 += __shfl_xor(a0, 16); a1 += __shfl_xor(a1, 16); a2 += __shfl_xor(a2, 16); a3 += __shfl_xor(a3, 16);
        a4 += __shfl_xor(a4, 16); a5 += __shfl_xor(a5, 16); a6 += __shfl_xor(a6, 16); a7 += __shfl_xor(a7, 16);
        a0 += __shfl_xor(a0, 32); a1 += __shfl_xor(a1, 32); a2 += __shfl_xor(a2, 32); a3 += __shfl_xor(a3, 32);
        a4 += __shfl_xor(a4, 32); a5 += __shfl_xor(a5, 32); a6 += __shfl_xor(a6, 32); a7 += __shfl_xor(a7, 32);
        if (lane < 16) {
            uint4 o;
            o.x = (uint_t)f2bf(a0) | ((uint_t)f2bf(a1) << 16);
            o.y = (uint_t)f2bf(a2) | ((uint_t)f2bf(a3) << 16);
            o.z = (uint_t)f2bf(a4) | ((uint_t)f2bf(a5) << 16);
            o.w = (uint_t)f2bf(a6) | ((uint_t)f2bf(a7) << 16);
            *(uint4*)(&at[rl * ZLD + ch]) = o;
        }
    }
    __syncthreads();

    // ---- phase A: z-tile = relu(d*(A@w1)+b1)*d ; each wave does 2 of 8 n-tiles ----
    const int m = lane & 15, q = lane >> 4;
    float4_t acc[2];
    acc[0] = (float4_t){0.f, 0.f, 0.f, 0.f};
    acc[1] = (float4_t){0.f, 0.f, 0.f, 0.f};
    #pragma unroll
    for (int ks = 0; ks < 4; ++ks) {
        const int k0 = ks * 32 + q * 8;
        const short8_t a = *(const short8_t*)(&at[m * ZLD + k0]);
        #pragma unroll
        for (int t = 0; t < 2; ++t) {
            const int nt = wv * 2 + t;
            const short8_t b = *(const short8_t*)(w1t + (size_t)(nt * 16 + m) * HIDC + k0);
            acc[t] = __builtin_amdgcn_mfma_f32_16x16x32_bf16(a, b, acc[t], 0, 0, 0);
        }
    }
    #pragma unroll
    for (int reg = 0; reg < 4; ++reg) {
        const int r = q * 4 + reg;
        const float d = deg[row0 + r];
        #pragma unroll
        for (int t = 0; t < 2; ++t) {
            const int col = (wv * 2 + t) * 16 + m;
            float v = fmaf(d, acc[t][reg], b1[col]);
            zt[r * ZLD + col] = f2bf(fmaxf(v, 0.f) * d);   // relu + fold layer-2 left d-scale
        }
    }
    __syncthreads();

    // ---- phase B: h2-tile = z @ w2 ; each wave does 1 of 4 n-tiles ----
    float4_t acc2 = (float4_t){0.f, 0.f, 0.f, 0.f};
    #pragma unroll
    for (int ks = 0; ks < 4; ++ks) {
        const int k0 = ks * 32 + q * 8;
        const short8_t a = *(const short8_t*)(&zt[m * ZLD + k0]);
        const short8_t b = *(const short8_t*)(w2t + (size_t)(wv * 16 + m) * HIDC + k0);
        acc2 = __builtin_amdgcn_mfma_f32_16x16x32_bf16(a, b, acc2, 0, 0, 0);
    }
    #pragma unroll
    for (int reg = 0; reg < 4; ++reg) {
        const int row = row0 + q * 4 + reg;
        h2[(size_t)row * OUTC + wv * 16 + m] = f2bf(acc2[reg]);
    }
}

// ===== layer-2 gather + epilogue: out[r] = deg[r]*sum(h2[col<NOWNED]) + b2 =====
__global__ __launch_bounds__(256) void gather2_k(const ushort_t* __restrict__ h2,
                                                 const float* __restrict__ deg,
                                                 const float* __restrict__ b2,
                                                 const int* __restrict__ cnt,
                                                 const ushort_t* __restrict__ cols_pad,
                                                 float* __restrict__ out) {
    const int w = __builtin_amdgcn_readfirstlane((blockIdx.x * 256 + threadIdx.x) >> 6);
    if (w >= NOWNED) return;
    const int lane = threadIdx.x & 63;
    const int q4 = lane >> 4;
    const int ch = (lane & 15) << 2;            // 4 channels per lane (8 B)
    int n = cnt[w];
    n = (n > CAP) ? CAP : n;
    const uint2* cp = (const uint2*)(cols_pad + w * CAP);
    const int nIter = (n + 3) >> 2;
    float a0 = 0.f, a1 = 0.f, a2 = 0.f, a3 = 0.f;
    uint2 cc = (nIter > 0) ? cp[0] : make_uint2(0, 0);
    for (int j = 0; j < nIter; ++j) {
        const uint2 cn = cp[(j + 1 < 16) ? j + 1 : 15];
        const int e = j * 4 + q4;
        int myc = (q4 == 0) ? (int)(cc.x & 0xFFFF) :
                  (q4 == 1) ? (int)(cc.x >> 16) :
                  (q4 == 2) ? (int)(cc.y & 0xFFFF) : (int)(cc.y >> 16);
        const float wgt = (e < n && myc < NOWNED) ? 1.f : 0.f;  // halo rows of x2 are zero
        myc = (e < n && myc < NOWNED) ? myc : 0;
        const uint2 v = *(const uint2*)(h2 + (size_t)myc * OUTC + ch);
        a0 = fmaf(wgt, bflo(v.x), a0);  a1 = fmaf(wgt, bfhi(v.x), a1);
        a2 = fmaf(wgt, bflo(v.y), a2);  a3 = fmaf(wgt, bfhi(v.y), a3);
        cc = cn;
    }
    a0 += __shfl_xor(a0, 16); a1 += __shfl_xor(a1, 16); a2 += __shfl_xor(a2, 16); a3 += __shfl_xor(a3, 16);
    a0 += __shfl_xor(a0, 32); a1 += __shfl_xor(a1, 32); a2 += __shfl_xor(a2, 32); a3 += __shfl_xor(a3, 32);
    if (lane < 16) {
        const float d = deg[w];
        const float4 o = make_float4(fmaf(d, a0, b2[ch]),     fmaf(d, a1, b2[ch + 1]),
                                     fmaf(d, a2, b2[ch + 2]), fmaf(d, a3, b2[ch + 3]));
        *(float4*)(out + (size_t)w * OUTC + ch) = o;
    }
}

extern "C" void kernel_launch(void* const* d_in, const int* in_sizes, int n_in,
                              void* d_out, int out_size, void* d_ws, size_t ws_size,
                              hipStream_t stream) {
    const float* x   = (const float*)d_in[0];
    const float* deg = (const float*)d_in[1];
    const float* w1  = (const float*)d_in[2];
    const float* b1  = (const float*)d_in[3];
    const float* w2  = (const float*)d_in[4];
    const float* b2  = (const float*)d_in[5];
    const int* er    = (const int*)d_in[6];
    const int* ec    = (const int*)d_in[7];
    float* out = (float*)d_out;

    char* ws = (char*)d_ws;
    ushort_t* xd       = (ushort_t*)(ws);              // 14.08 MB [NLOCAL x 128] bf16
    ushort_t* cols_pad = (ushort_t*)(ws + 14080000);   // 6.41 MB  [NROWS_PAD x CAP] ushort
    int* cnt           = (int*)(ws + 20486144);        // 200 KB   [NROWS_PAD]
    ushort_t* h2       = (ushort_t*)(ws + 20686336);   // 6.4 MB   [NOWNED x 64] bf16
    ushort_t* w1t      = (ushort_t*)(ws + 27086336);   // 32 KB    [128 x 128] bf16
    ushort_t* w2t      = (ushort_t*)(ws + 27119104);   // 16 KB    [64 x 128] bf16
    uint_t* bbuf       = (uint_t*)(ws + 27135488);     // 25.6 MB  [NB x NBUCK x BCAP]
    int* bcnt2         = (int*)(ws + 52760064);        // 400 KB   [NB x NBUCK]

    prep_k<<<(NLOCAL * 32 + 255) / 256, 256, 0, stream>>>(x, deg, w1, w2, xd, w1t, w2t);
    bin_k<<<NB, 256, 0, stream>>>(er, ec, bcnt2, bbuf);
    csr_k<<<NBUCK, 256, 0, stream>>>(bcnt2, bbuf, cnt, cols_pad);
    gg_k<<<NSTRIPS, 256, 0, stream>>>(xd, cnt, cols_pad, w1t, w2t, b1, deg, h2);
    gather2_k<<<(NOWNED * 64 + 255) / 256, 256, 0, stream>>>(h2, deg, b2, cnt, cols_pad, out);
}

// Round 11
// 170.750 us; speedup vs baseline: 1.3080x; 1.0593x over previous
//
#include <hip/hip_runtime.h>

#define NLOCAL 55000
#define NOWNED 50000
#define NEDGES 800000
#define INC 128
#define HIDC 128
#define OUTC 64
#define CAP 64            // per-row CSR capacity (deg ~ Binom mean 14.5; P(>64) ~ 1e-15)
#define NSTRIPS (NOWNED / 16)   // 3125
#define ZLD 136           // LDS tile row stride in shorts (+8 pad)
#define NB 256            // bin_k blocks (private regions)
#define EPB (NEDGES / NB) // 3125 edges per bin block
#define NBUCK 391         // row buckets of 128 rows (50048 padded rows)
#define BROWS 128
#define BCAP 64           // per (block,bucket) capacity (mean 8; P(>64) ~ 1e-20)
#define NROWS_PAD (NBUCK * BROWS)   // 50048

typedef unsigned short ushort_t;
typedef unsigned int uint_t;
typedef short short8_t __attribute__((ext_vector_type(8)));
typedef float float4_t __attribute__((ext_vector_type(4)));

static __device__ __forceinline__ ushort_t f2bf(float f) {   // RNE fp32->bf16
    uint_t u = __float_as_uint(f);
    return (ushort_t)((u + 0x7FFFu + ((u >> 16) & 1u)) >> 16);
}
static __device__ __forceinline__ float bflo(uint_t v) { return __uint_as_float(v << 16); }
static __device__ __forceinline__ float bfhi(uint_t v) { return __uint_as_float(v & 0xFFFF0000u); }
static __device__ __forceinline__ int pick4(uint2 c, int q4) {
    return (q4 == 0) ? (int)(c.x & 0xFFFF) : (q4 == 1) ? (int)(c.x >> 16)
         : (q4 == 2) ? (int)(c.y & 0xFFFF) : (int)(c.y >> 16);
}

// ======= prep: xd = bf16(deg*x); transpose w1,w2 to bf16 [n][k] =======
__global__ __launch_bounds__(256) void prep_k(const float* __restrict__ x,
                                              const float* __restrict__ deg,
                                              const float* __restrict__ w1,
                                              const float* __restrict__ w2,
                                              ushort_t* __restrict__ xd,
                                              ushort_t* __restrict__ w1t,
                                              ushort_t* __restrict__ w2t) {
    const int gid = blockIdx.x * 256 + threadIdx.x;
    if (gid < NLOCAL * 32) {                 // one float4 -> 4 bf16
        const int row = gid >> 5;
        const int c0 = (gid & 31) << 2;
        const float d = deg[row];
        const float4 v = *(const float4*)(x + (size_t)row * INC + c0);
        uint_t lo = (uint_t)f2bf(v.x * d) | ((uint_t)f2bf(v.y * d) << 16);
        uint_t hi = (uint_t)f2bf(v.z * d) | ((uint_t)f2bf(v.w * d) << 16);
        *(uint2*)(xd + (size_t)row * INC + c0) = make_uint2(lo, hi);
    }
    if (gid < HIDC * INC) {                  // w1 [K][N=128] -> w1t [N][K]
        const int k = gid >> 7, n = gid & 127;
        w1t[n * 128 + k] = f2bf(w1[gid]);
    } else if (gid < HIDC * INC + HIDC * OUTC) {   // w2 [K][N=64] -> w2t [N][K]
        const int j = gid - HIDC * INC;
        const int k = j >> 6, n = j & 63;
        w2t[n * 128 + k] = f2bf(w2[j]);
    }
}

// ===== pass 1: bin edges into per-BLOCK-private bucket regions (no global atomics) =====
__global__ __launch_bounds__(256) void bin_k(const int* __restrict__ er,
                                             const int* __restrict__ ec,
                                             int* __restrict__ bcnt2,
                                             uint_t* __restrict__ bbuf) {
    __shared__ int lcnt[NBUCK];
    const int k = blockIdx.x;
    for (int b = threadIdx.x; b < NBUCK; b += 256) lcnt[b] = 0;
    __syncthreads();
    const int e0 = k * EPB;
    for (int i = threadIdx.x; i < EPB; i += 256) {
        const int e = e0 + i;
        const int row = er[e];
        if (row >= NOWNED) continue;            // only owned destination rows matter
        const int col = ec[e];
        const int b = row >> 7;
        const int p = atomicAdd(&lcnt[b], 1);   // LDS atomic
        if (p < BCAP)
            bbuf[((size_t)k * NBUCK + b) * BCAP + p] = ((uint_t)(row & 127) << 16) | (uint_t)col;
    }
    __syncthreads();
    for (int b = threadIdx.x; b < NBUCK; b += 256) {
        const int c = lcnt[b];
        bcnt2[k * NBUCK + b] = (c > BCAP) ? BCAP : c;
    }
}

// ===== pass 2: bucket -> padded CSR; all global writes are coalesced streaming =====
__global__ __launch_bounds__(256) void csr_k(const int* __restrict__ bcnt2,
                                             const uint_t* __restrict__ bbuf,
                                             int* __restrict__ cnt,
                                             ushort_t* __restrict__ cols_pad) {
    __shared__ int lcnt[BROWS];
    __shared__ ushort_t lcols[BROWS * CAP];     // 16 KB
    const int b = blockIdx.x;
    const int t = threadIdx.x;                  // == region index (NB == 256)
    if (t < BROWS) lcnt[t] = 0;
    __syncthreads();
    const int n = bcnt2[t * NBUCK + b];
    const uint_t* src = bbuf + ((size_t)t * NBUCK + b) * BCAP;
    for (int i = 0; i < n; ++i) {
        const uint_t v = src[i];
        const int rl = (int)(v >> 16);
        const int p = atomicAdd(&lcnt[rl], 1);
        if (p < CAP) lcols[rl * CAP + p] = (ushort_t)(v & 0xFFFFu);
    }
    __syncthreads();
    const int row0 = b * BROWS;
    if (t < BROWS) {
        const int c = lcnt[t];
        cnt[row0 + t] = (c > CAP) ? CAP : c;
    }
    const uint4* ls = (const uint4*)lcols;      // 1024 x 16B
    uint4* gd = (uint4*)(cols_pad + (size_t)row0 * CAP);
    #pragma unroll
    for (int i = 0; i < BROWS * CAP / 8 / 256; ++i)   // 4 per thread
        gd[t + i * 256] = ls[t + i * 256];      // streaming, full lines
}

// ===== fused gather1 + gemm1 + gemm2 per 16-row strip =====
// phase 0: 4 waves x 4 rows, edge streams INTERLEAVED (4 independent loads in
//   flight per round) — row-sums of xd[col] go straight into LDS A-tile (bf16)
// phase A: z-tile = relu(d*(A@w1)+b1)*d -> LDS ;  phase B: h2 = bf16(z @ w2)
__global__ __launch_bounds__(256) void gg_k(const ushort_t* __restrict__ xd,
                                            const int* __restrict__ cnt,
                                            const ushort_t* __restrict__ cols_pad,
                                            const ushort_t* __restrict__ w1t,
                                            const ushort_t* __restrict__ w2t,
                                            const float* __restrict__ b1,
                                            const float* __restrict__ deg,
                                            ushort_t* __restrict__ h2) {
    __shared__ ushort_t at[16 * ZLD];           // gathered A-tile
    __shared__ ushort_t zt[16 * ZLD];           // layer-1 output tile
    const int lane = threadIdx.x & 63;
    const int wv = __builtin_amdgcn_readfirstlane(threadIdx.x >> 6);
    const int row0 = blockIdx.x * 16;
    const int q4 = lane >> 4;                   // quarter: edge 4j+q4
    const int ch = (lane & 15) << 3;            // 8 channels per lane (16 B)

    // ---- phase 0: 4 rows per wave, interleaved ----
    float ac[4][8];
    #pragma unroll
    for (int i = 0; i < 4; ++i)
        #pragma unroll
        for (int c = 0; c < 8; ++c) ac[i][c] = 0.f;
    int nn[4];
    const uint2* cp[4];
    uint2 cc[4];
    int nIterMax = 0;
    #pragma unroll
    for (int i = 0; i < 4; ++i) {
        const int w = row0 + wv * 4 + i;        // wave-uniform
        int n = cnt[w];
        nn[i] = (n > CAP) ? CAP : n;
        cp[i] = (const uint2*)(cols_pad + (size_t)w * CAP);
        cc[i] = cp[i][0];
        const int it = (nn[i] + 3) >> 2;
        nIterMax = (it > nIterMax) ? it : nIterMax;
    }
    for (int j = 0; j < nIterMax; ++j) {
        const int e = j * 4 + q4;
        const int jn = (j + 1 < 16) ? j + 1 : 15;
        #pragma unroll
        for (int i = 0; i < 4; ++i) {           // 4 independent gathers in flight
            int myc = pick4(cc[i], q4);
            const float wgt = (e < nn[i]) ? 1.f : 0.f;
            myc = (e < nn[i]) ? myc : 0;
            const uint4 v = *(const uint4*)(xd + (size_t)myc * INC + ch);
            ac[i][0] = fmaf(wgt, bflo(v.x), ac[i][0]);  ac[i][1] = fmaf(wgt, bfhi(v.x), ac[i][1]);
            ac[i][2] = fmaf(wgt, bflo(v.y), ac[i][2]);  ac[i][3] = fmaf(wgt, bfhi(v.y), ac[i][3]);
            ac[i][4] = fmaf(wgt, bflo(v.z), ac[i][4]);  ac[i][5] = fmaf(wgt, bfhi(v.z), ac[i][5]);
            ac[i][6] = fmaf(wgt, bflo(v.w), ac[i][6]);  ac[i][7] = fmaf(wgt, bfhi(v.w), ac[i][7]);
        }
        #pragma unroll
        for (int i = 0; i < 4; ++i) cc[i] = cp[i][jn];   // scalar prefetch for next round
    }
    #pragma unroll
    for (int i = 0; i < 4; ++i) {
        #pragma unroll
        for (int c = 0; c < 8; ++c) {
            ac[i][c] += __shfl_xor(ac[i][c], 16);
            ac[i][c] += __shfl_xor(ac[i][c], 32);
        }
        if (lane < 16) {
            uint4 o;
            o.x = (uint_t)f2bf(ac[i][0]) | ((uint_t)f2bf(ac[i][1]) << 16);
            o.y = (uint_t)f2bf(ac[i][2]) | ((uint_t)f2bf(ac[i][3]) << 16);
            o.z = (uint_t)f2bf(ac[i][4]) | ((uint_t)f2bf(ac[i][5]) << 16);
            o.w = (uint_t)f2bf(ac[i][6]) | ((uint_t)f2bf(ac[i][7]) << 16);
            *(uint4*)(&at[(wv * 4 + i) * ZLD + ch]) = o;
        }
    }
    __syncthreads();

    // ---- phase A: z-tile = relu(d*(A@w1)+b1)*d ; each wave does 2 of 8 n-tiles ----
    const int m = lane & 15, q = lane >> 4;
    float4_t acc[2];
    acc[0] = (float4_t){0.f, 0.f, 0.f, 0.f};
    acc[1] = (float4_t){0.f, 0.f, 0.f, 0.f};
    #pragma unroll
    for (int ks = 0; ks < 4; ++ks) {
        const int k0 = ks * 32 + q * 8;
        const short8_t a = *(const short8_t*)(&at[m * ZLD + k0]);
        #pragma unroll
        for (int t = 0; t < 2; ++t) {
            const int nt = wv * 2 + t;
            const short8_t b = *(const short8_t*)(w1t + (size_t)(nt * 16 + m) * HIDC + k0);
            acc[t] = __builtin_amdgcn_mfma_f32_16x16x32_bf16(a, b, acc[t], 0, 0, 0);
        }
    }
    #pragma unroll
    for (int reg = 0; reg < 4; ++reg) {
        const int r = q * 4 + reg;
        const float d = deg[row0 + r];
        #pragma unroll
        for (int t = 0; t < 2; ++t) {
            const int col = (wv * 2 + t) * 16 + m;
            float v = fmaf(d, acc[t][reg], b1[col]);
            zt[r * ZLD + col] = f2bf(fmaxf(v, 0.f) * d);   // relu + fold layer-2 left d-scale
        }
    }
    __syncthreads();

    // ---- phase B: h2-tile = z @ w2 ; each wave does 1 of 4 n-tiles ----
    float4_t acc2 = (float4_t){0.f, 0.f, 0.f, 0.f};
    #pragma unroll
    for (int ks = 0; ks < 4; ++ks) {
        const int k0 = ks * 32 + q * 8;
        const short8_t a = *(const short8_t*)(&zt[m * ZLD + k0]);
        const short8_t b = *(const short8_t*)(w2t + (size_t)(wv * 16 + m) * HIDC + k0);
        acc2 = __builtin_amdgcn_mfma_f32_16x16x32_bf16(a, b, acc2, 0, 0, 0);
    }
    #pragma unroll
    for (int reg = 0; reg < 4; ++reg) {
        const int row = row0 + q * 4 + reg;
        h2[(size_t)row * OUTC + wv * 16 + m] = f2bf(acc2[reg]);
    }
}

// ===== layer-2 gather + epilogue: out[r] = deg[r]*sum(h2[col<NOWNED]) + b2 =====
// 4 rows per wave, interleaved streams; 4 ch/lane (8 B)
__global__ __launch_bounds__(256) void gather2_k(const ushort_t* __restrict__ h2,
                                                 const float* __restrict__ deg,
                                                 const float* __restrict__ b2,
                                                 const int* __restrict__ cnt,
                                                 const ushort_t* __restrict__ cols_pad,
                                                 float* __restrict__ out) {
    const int wbase = __builtin_amdgcn_readfirstlane(((blockIdx.x * 256 + threadIdx.x) >> 6) * 4);
    if (wbase >= NOWNED) return;
    const int lane = threadIdx.x & 63;
    const int q4 = lane >> 4;
    const int ch = (lane & 15) << 2;            // 4 channels per lane (8 B)
    float ac[4][4];
    #pragma unroll
    for (int i = 0; i < 4; ++i)
        #pragma unroll
        for (int c = 0; c < 4; ++c) ac[i][c] = 0.f;
    int nn[4];
    const uint2* cp[4];
    uint2 cc[4];
    int nIterMax = 0;
    #pragma unroll
    for (int i = 0; i < 4; ++i) {
        const int w = wbase + i;
        int n = cnt[w];
        nn[i] = (n > CAP) ? CAP : n;
        cp[i] = (const uint2*)(cols_pad + (size_t)w * CAP);
        cc[i] = cp[i][0];
        const int it = (nn[i] + 3) >> 2;
        nIterMax = (it > nIterMax) ? it : nIterMax;
    }
    for (int j = 0; j < nIterMax; ++j) {
        const int e = j * 4 + q4;
        const int jn = (j + 1 < 16) ? j + 1 : 15;
        #pragma unroll
        for (int i = 0; i < 4; ++i) {
            int myc = pick4(cc[i], q4);
            const float wgt = (e < nn[i] && myc < NOWNED) ? 1.f : 0.f;  // halo rows of x2 are zero
            myc = (e < nn[i] && myc < NOWNED) ? myc : 0;
            const uint2 v = *(const uint2*)(h2 + (size_t)myc * OUTC + ch);
            ac[i][0] = fmaf(wgt, bflo(v.x), ac[i][0]);  ac[i][1] = fmaf(wgt, bfhi(v.x), ac[i][1]);
            ac[i][2] = fmaf(wgt, bflo(v.y), ac[i][2]);  ac[i][3] = fmaf(wgt, bfhi(v.y), ac[i][3]);
        }
        #pragma unroll
        for (int i = 0; i < 4; ++i) cc[i] = cp[i][jn];
    }
    #pragma unroll
    for (int i = 0; i < 4; ++i) {
        #pragma unroll
        for (int c = 0; c < 4; ++c) {
            ac[i][c] += __shfl_xor(ac[i][c], 16);
            ac[i][c] += __shfl_xor(ac[i][c], 32);
        }
        if (lane < 16) {
            const int w = wbase + i;
            const float d = deg[w];
            const float4 o = make_float4(fmaf(d, ac[i][0], b2[ch]),     fmaf(d, ac[i][1], b2[ch + 1]),
                                         fmaf(d, ac[i][2], b2[ch + 2]), fmaf(d, ac[i][3], b2[ch + 3]));
            *(float4*)(out + (size_t)w * OUTC + ch) = o;
        }
    }
}

extern "C" void kernel_launch(void* const* d_in, const int* in_sizes, int n_in,
                              void* d_out, int out_size, void* d_ws, size_t ws_size,
                              hipStream_t stream) {
    const float* x   = (const float*)d_in[0];
    const float* deg = (const float*)d_in[1];
    const float* w1  = (const float*)d_in[2];
    const float* b1  = (const float*)d_in[3];
    const float* w2  = (const float*)d_in[4];
    const float* b2  = (const float*)d_in[5];
    const int* er    = (const int*)d_in[6];
    const int* ec    = (const int*)d_in[7];
    float* out = (float*)d_out;

    char* ws = (char*)d_ws;
    ushort_t* xd       = (ushort_t*)(ws);              // 14.08 MB [NLOCAL x 128] bf16
    ushort_t* cols_pad = (ushort_t*)(ws + 14080000);   // 6.41 MB  [NROWS_PAD x CAP] ushort
    int* cnt           = (int*)(ws + 20486144);        // 200 KB   [NROWS_PAD]
    ushort_t* h2       = (ushort_t*)(ws + 20686336);   // 6.4 MB   [NOWNED x 64] bf16
    ushort_t* w1t      = (ushort_t*)(ws + 27086336);   // 32 KB    [128 x 128] bf16
    ushort_t* w2t      = (ushort_t*)(ws + 27119104);   // 16 KB    [64 x 128] bf16
    uint_t* bbuf       = (uint_t*)(ws + 27135488);     // 25.6 MB  [NB x NBUCK x BCAP]
    int* bcnt2         = (int*)(ws + 52760064);        // 400 KB   [NB x NBUCK]

    prep_k<<<(NLOCAL * 32 + 255) / 256, 256, 0, stream>>>(x, deg, w1, w2, xd, w1t, w2t);
    bin_k<<<NB, 256, 0, stream>>>(er, ec, bcnt2, bbuf);
    csr_k<<<NBUCK, 256, 0, stream>>>(bcnt2, bbuf, cnt, cols_pad);
    gg_k<<<NSTRIPS, 256, 0, stream>>>(xd, cnt, cols_pad, w1t, w2t, b1, deg, h2);
    gather2_k<<<(NOWNED / 4 * 64 + 255) / 256, 256, 0, stream>>>(h2, deg, b2, cnt, cols_pad, out);
}